// Round 1
// baseline (285.036 us; speedup 1.0000x reference)
//
#include <hip/hip_runtime.h>
#include <math.h>

#define DEV __device__ __forceinline__

constexpr int NTOK = 1024;
constexpr int D    = 512;
constexpr int H    = 8;
constexpr int HD   = 64;
constexpr int S    = 64;
constexpr int NB   = NTOK / S;   // 16
constexpr double EPSd = 1e-7;

// ---------------- reductions ----------------
DEV double wave_sum(double v) {
#pragma unroll
  for (int m = 32; m; m >>= 1) v += __shfl_xor(v, m, 64);
  return v;
}

// blockDim.x == 256 (4 waves)
DEV double block_sum(double v, double* scratch) {
  v = wave_sum(v);
  __syncthreads();                      // protect scratch reuse (WAR)
  if ((threadIdx.x & 63) == 0) scratch[threadIdx.x >> 6] = v;
  __syncthreads();
  return scratch[0] + scratch[1] + scratch[2] + scratch[3];
}

// ---------------- phase 1: logmap0 -> LN -> expmap0 -> logmap0 (fused) ----------------
__global__ void k_pre(const float* __restrict__ x, const float* __restrict__ cg,
                      const float* __restrict__ s1, const float* __restrict__ b1,
                      float* __restrict__ xt) {
  __shared__ double scratch[4];
  const int tok = blockIdx.x;
  const int t = threadIdx.x;
  const float* row = x + (size_t)tok * D;
  float v0 = row[t], v1 = row[t + 256];
  double c = (double)cg[0];
  double sc = sqrt(c); if (sc < EPSd) sc = EPSd;

  // logmap0(xb, c)
  double yn = sqrt(block_sum((double)v0 * v0 + (double)v1 * v1, scratch));
  double arg0 = yn; if (arg0 > 1.0 - EPSd) arg0 = 1.0 - EPSd;
  double f = (yn < EPSd) ? 0.0 : atanh(arg0) / sc / fmax(yn, EPSd);
  double u0 = f * v0, u1 = f * v1;

  // layernorm (eps = 1e-6)
  double mu  = block_sum(u0 + u1, scratch) / D;
  double su2 = block_sum(u0 * u0 + u1 * u1, scratch);
  double var = su2 / D - mu * mu;
  double rs = 1.0 / sqrt(var + 1e-6);
  double w0 = (u0 - mu) * rs * (double)s1[t]       + (double)b1[t];
  double w1 = (u1 - mu) * rs * (double)s1[t + 256] + (double)b1[t + 256];

  // fused expmap0 -> logmap0 : t = F * w  (projection preserved analytically)
  double vn = sqrt(block_sum(w0 * w0 + w1 * w1, scratch));
  double F = 0.0;
  if (vn >= EPSd) {
    double mag_e = tanh(sc * fmax(vn, EPSd)) / sc;   // norm of expmap0 output (pre-project)
    double a2 = fmin(mag_e, 1.0 - EPSd);             // project + logmap0 clamp combined
    F = atanh(a2) / (sc * vn);
  }
  xt[(size_t)tok * D + t]       = (float)(F * w0);
  xt[(size_t)tok * D + t + 256] = (float)(F * w1);
}

// ---------------- generic fp32 tiled GEMM: C = A[M,K] @ B[K,N] + bias, optional GELU ----------------
template <int GELU>
__global__ void k_gemm(const float* __restrict__ A, const float* __restrict__ B,
                       const float* __restrict__ bias, float* __restrict__ C,
                       int M, int N, int K) {
  __shared__ float As[16][64];
  __shared__ float Bs[16][64];
  const int tid = threadIdx.x;
  const int tx = tid & 15, ty = tid >> 4;
  const int c0 = blockIdx.x * 64, r0 = blockIdx.y * 64;
  const int ar = tid >> 2;          // A row within tile
  const int ac = (tid & 3) * 4;     // A k-col within tile
  const int bk = tid >> 4;          // B k-row within tile
  const int bc = (tid & 15) * 4;    // B col within tile
  float acc[4][4] = {};
  for (int k0 = 0; k0 < K; k0 += 16) {
    float4 av = *(const float4*)(A + (size_t)(r0 + ar) * K + k0 + ac);
    float4 bv = *(const float4*)(B + (size_t)(k0 + bk) * N + c0 + bc);
    As[ac + 0][ar] = av.x; As[ac + 1][ar] = av.y;
    As[ac + 2][ar] = av.z; As[ac + 3][ar] = av.w;
    *(float4*)(&Bs[bk][bc]) = bv;
    __syncthreads();
#pragma unroll
    for (int kk = 0; kk < 16; ++kk) {
      float4 a = *(const float4*)(&As[kk][ty * 4]);
      float4 b = *(const float4*)(&Bs[kk][tx * 4]);
      float aa[4] = {a.x, a.y, a.z, a.w};
      float bb[4] = {b.x, b.y, b.z, b.w};
#pragma unroll
      for (int i = 0; i < 4; ++i)
#pragma unroll
        for (int j = 0; j < 4; ++j) acc[i][j] += aa[i] * bb[j];
    }
    __syncthreads();
  }
#pragma unroll
  for (int i = 0; i < 4; ++i) {
    int r = r0 + ty * 4 + i;
#pragma unroll
    for (int j = 0; j < 4; ++j) {
      int cc = c0 + tx * 4 + j;
      float v = acc[i][j] + bias[cc];
      if (GELU) {
        float x3 = v * v * v;
        v = 0.5f * v * (1.0f + tanhf(0.7978845608028654f * (v + 0.044715f * x3)));
      }
      C[(size_t)r * N + cc] = v;
    }
  }
}

// ---------------- phase 3: RoPE + per-head expmap0 for q,k ----------------
__global__ void k_rope(const float* __restrict__ qkv, const float* __restrict__ chl,
                       float* __restrict__ qh, float* __restrict__ kh) {
  const int lane = threadIdx.x & 63;
  const int wid  = threadIdx.x >> 6;
  const int gw   = blockIdx.x * 4 + wid;   // (token, head) pair index
  const int tok  = gw >> 3;
  const int h    = gw & 7;
  const int pos  = tok & (S - 1);
  const float* base = qkv + (size_t)tok * (3 * D) + h * HD;
  float qv = base[lane];
  float kv = base[D + lane];
  int j = lane & 31;
  double fj = exp(-log(10000.0) * (double)j / 32.0);
  double th = (double)pos * fj;
  double cth = cos(th), sth = sin(th);
  float qo = __shfl_xor(qv, 32, 64);
  float ko = __shfl_xor(kv, 32, 64);
  double qr, kr;
  if (lane < 32) { qr = (double)qv * cth - (double)qo * sth;
                   kr = (double)kv * cth - (double)ko * sth; }
  else           { qr = (double)qo * sth + (double)qv * cth;
                   kr = (double)ko * sth + (double)kv * cth; }
  double ch = log1p(exp((double)chl[h]));      // softplus
  double sc = sqrt(ch); if (sc < EPSd) sc = EPSd;
  // expmap0 (with projection)
  double qn = sqrt(wave_sum(qr * qr));
  double mq = tanh(sc * fmax(qn, EPSd)) / sc;
  double fq = (qn < EPSd) ? 0.0 : mq / fmax(qn, EPSd);
  if (mq >= 1.0) fq *= (1.0 - EPSd) / mq;
  double kn = sqrt(wave_sum(kr * kr));
  double mk = tanh(sc * fmax(kn, EPSd)) / sc;
  double fk = (kn < EPSd) ? 0.0 : mk / fmax(kn, EPSd);
  if (mk >= 1.0) fk *= (1.0 - EPSd) / mk;
  qh[(size_t)tok * D + h * HD + lane] = (float)(qr * fq);
  kh[(size_t)tok * D + h * HD + lane] = (float)(kr * fk);
}

// ---------------- phase 4: hyperbolic-distance attention per (block, head) ----------------
__global__ void k_attn(const float* __restrict__ qh, const float* __restrict__ kh,
                       const float* __restrict__ qkv, const float* __restrict__ chl,
                       const float* __restrict__ geo, float* __restrict__ ao) {
  __shared__ float Qs[64][65];
  __shared__ float Ks[64][65];
  __shared__ double q2s[64], k2s[64];
  const int be = blockIdx.x >> 3;
  const int h  = blockIdx.x & 7;
  const int tid = threadIdx.x;
  for (int l = tid; l < 64 * 64; l += 256) {
    int s = l >> 6, d = l & 63;
    Qs[s][d] = qh[(size_t)(be * 64 + s) * D + h * HD + d];
    Ks[s][d] = kh[(size_t)(be * 64 + s) * D + h * HD + d];
  }
  __syncthreads();
  if (tid < 64) {
    double acc = 0;
    for (int d = 0; d < 64; ++d) { double q = Qs[tid][d]; acc += q * q; }
    q2s[tid] = acc;
  } else if (tid < 128) {
    int i = tid - 64; double acc = 0;
    for (int d = 0; d < 64; ++d) { double k = Ks[i][d]; acc += k * k; }
    k2s[i] = acc;
  }
  __syncthreads();
  const int i = tid >> 2, g = tid & 3;   // row i, 16-col group g
  float gacc[16];
#pragma unroll
  for (int jj = 0; jj < 16; ++jj) gacc[jj] = 0.f;
  for (int d = 0; d < 64; ++d) {
    float qv = Qs[i][d];
#pragma unroll
    for (int jj = 0; jj < 16; ++jj) gacc[jj] += qv * Ks[g * 16 + jj][d];
  }
  // distances -> logits
  double ch = log1p(exp((double)chl[h]));
  double sc = sqrt(ch); if (sc < EPSd) sc = EPSd;
  double gs = (double)geo[h];
  double q2 = q2s[i];
  float lg[16];
  float mx = -1e30f;
#pragma unroll
  for (int jj = 0; jj < 16; ++jj) {
    double gq = (double)gacc[jj];
    double k2 = k2s[g * 16 + jj];
    double A  = 1.0 - 2.0 * ch * gq + ch * k2;
    double Bv = 1.0 - ch * q2;
    double n2 = A * A * q2 - 2.0 * A * Bv * gq + Bv * Bv * k2;
    if (n2 < 0.0) n2 = 0.0;
    double den = 1.0 - 2.0 * ch * gq + ch * ch * q2 * k2;
    if (den < EPSd) den = EPSd;
    double r = sqrt(n2) / den;
    if (r >= 1.0) r = 1.0 - EPSd;            // project inside mobius_add
    double arg = sc * r; if (arg > 1.0 - EPSd) arg = 1.0 - EPSd;
    double dist = 2.0 * atanh(arg) / sc;
    float l = (float)(-gs * dist);
    lg[jj] = l; mx = fmaxf(mx, l);
  }
  // softmax across the 4 threads holding row i (consecutive lanes)
  mx = fmaxf(mx, __shfl_xor(mx, 1, 64));
  mx = fmaxf(mx, __shfl_xor(mx, 2, 64));
  float pv[16]; float sum = 0.f;
#pragma unroll
  for (int jj = 0; jj < 16; ++jj) { pv[jj] = expf(lg[jj] - mx); sum += pv[jj]; }
  sum += __shfl_xor(sum, 1, 64);
  sum += __shfl_xor(sum, 2, 64);
  float inv = 1.0f / sum;
  __syncthreads();                           // done reading Qs/Ks for scores
  // P into Qs, V into Ks
#pragma unroll
  for (int jj = 0; jj < 16; ++jj) Qs[i][g * 16 + jj] = pv[jj] * inv;
  for (int l = tid; l < 64 * 64; l += 256) {
    int s = l >> 6, d = l & 63;
    Ks[s][d] = qkv[(size_t)(be * 64 + s) * (3 * D) + 2 * D + h * HD + d];
  }
  __syncthreads();
  float oacc[16];
#pragma unroll
  for (int dd = 0; dd < 16; ++dd) oacc[dd] = 0.f;
  for (int jv = 0; jv < 64; ++jv) {
    float p = Qs[i][jv];
#pragma unroll
    for (int dd = 0; dd < 16; ++dd) oacc[dd] += p * Ks[jv][g * 16 + dd];
  }
#pragma unroll
  for (int dd = 0; dd < 16; ++dd)
    ao[(size_t)(be * 64 + i) * D + h * HD + g * 16 + dd] = oacc[dd];
}

// ---------------- phase 6: expmap0(proj) -> mobius residual -> norm2 chain ----------------
__global__ void k_resid(const float* __restrict__ x, const float* __restrict__ proj,
                        const float* __restrict__ cg, const float* __restrict__ s2,
                        const float* __restrict__ b2, float* __restrict__ xa,
                        float* __restrict__ t2) {
  __shared__ double scratch[4];
  const int tok = blockIdx.x, t = threadIdx.x;
  const float* xr = x    + (size_t)tok * D;
  const float* pr = proj + (size_t)tok * D;
  float x0 = xr[t], x1 = xr[t + 256];
  float p0 = pr[t], p1 = pr[t + 256];
  double c = (double)cg[0];
  double sc = sqrt(c); if (sc < EPSd) sc = EPSd;
  double xx = block_sum((double)x0 * x0 + (double)x1 * x1, scratch);
  double pp = block_sum((double)p0 * p0 + (double)p1 * p1, scratch);
  double xp = block_sum((double)x0 * p0 + (double)x1 * p1, scratch);
  // ah = expmap0(proj) = fs * proj
  double pn = sqrt(pp);
  double me = tanh(sc * fmax(pn, EPSd)) / sc;
  double fs = (pn < EPSd) ? 0.0 : me / fmax(pn, EPSd);
  if (me >= 1.0) fs *= (1.0 - EPSd) / me;
  // mobius_add(x, ah, c), all scalar coefficients analytic
  double y2 = fs * fs * pp, xy = fs * xp;
  double a = 1.0 + 2.0 * c * xy + c * y2;
  double b = 1.0 - c * xx;
  double den = 1.0 + 2.0 * c * xy + c * c * xx * y2;
  if (den < EPSd) den = EPSd;
  double zn = sqrt(fmax(a * a * xx + 2.0 * a * b * xy + b * b * y2, 0.0)) / den;
  double zs = 1.0 / den;
  if (zn >= 1.0) zs *= (1.0 - EPSd) / zn;
  double xan = (zn >= 1.0) ? (1.0 - EPSd) : zn;
  double A0 = zs * a, B0 = zs * b * fs;
  double xa0 = A0 * x0 + B0 * p0, xa1 = A0 * x1 + B0 * p1;
  xa[(size_t)tok * D + t]       = (float)xa0;
  xa[(size_t)tok * D + t + 256] = (float)xa1;
  // logmap0(xa)
  double fl = 0.0;
  if (xan >= EPSd) {
    double arg = fmin(xan, 1.0 - EPSd);
    fl = atanh(arg) / (sc * fmax(xan, EPSd));
  }
  double u0 = fl * xa0, u1 = fl * xa1;
  // layernorm (ln2)
  double mu  = block_sum(u0 + u1, scratch) / D;
  double su2 = block_sum(u0 * u0 + u1 * u1, scratch);
  double var = su2 / D - mu * mu;
  double rs = 1.0 / sqrt(var + 1e-6);
  double w0 = (u0 - mu) * rs * (double)s2[t]       + (double)b2[t];
  double w1 = (u1 - mu) * rs * (double)s2[t + 256] + (double)b2[t + 256];
  // fused expmap0 -> logmap0
  double vn = sqrt(block_sum(w0 * w0 + w1 * w1, scratch));
  double F = 0.0;
  if (vn >= EPSd) {
    double mag_e = tanh(sc * fmax(vn, EPSd)) / sc;
    double a2 = fmin(mag_e, 1.0 - EPSd);
    F = atanh(a2) / (sc * vn);
  }
  t2[(size_t)tok * D + t]       = (float)(F * w0);
  t2[(size_t)tok * D + t + 256] = (float)(F * w1);
}

// ---------------- phase 9: expmap0(ffn) -> mobius residual -> out ----------------
__global__ void k_final(const float* __restrict__ xa, const float* __restrict__ f2,
                        const float* __restrict__ cg, float* __restrict__ out) {
  __shared__ double scratch[4];
  const int tok = blockIdx.x, t = threadIdx.x;
  const float* ar = xa + (size_t)tok * D;
  const float* fr = f2 + (size_t)tok * D;
  float x0 = ar[t], x1 = ar[t + 256];
  float p0 = fr[t], p1 = fr[t + 256];
  double c = (double)cg[0];
  double sc = sqrt(c); if (sc < EPSd) sc = EPSd;
  double xx = block_sum((double)x0 * x0 + (double)x1 * x1, scratch);
  double pp = block_sum((double)p0 * p0 + (double)p1 * p1, scratch);
  double xp = block_sum((double)x0 * p0 + (double)x1 * p1, scratch);
  double pn = sqrt(pp);
  double me = tanh(sc * fmax(pn, EPSd)) / sc;
  double fs = (pn < EPSd) ? 0.0 : me / fmax(pn, EPSd);
  if (me >= 1.0) fs *= (1.0 - EPSd) / me;
  double y2 = fs * fs * pp, xy = fs * xp;
  double a = 1.0 + 2.0 * c * xy + c * y2;
  double b = 1.0 - c * xx;
  double den = 1.0 + 2.0 * c * xy + c * c * xx * y2;
  if (den < EPSd) den = EPSd;
  double zn = sqrt(fmax(a * a * xx + 2.0 * a * b * xy + b * b * y2, 0.0)) / den;
  double zs = 1.0 / den;
  if (zn >= 1.0) zs *= (1.0 - EPSd) / zn;
  double A0 = zs * a, B0 = zs * b * fs;
  out[(size_t)tok * D + t]       = (float)(A0 * x0 + B0 * p0);
  out[(size_t)tok * D + t + 256] = (float)(A0 * x1 + B0 * p1);
}

// ---------------- launch ----------------
extern "C" void kernel_launch(void* const* d_in, const int* in_sizes, int n_in,
                              void* d_out, int out_size, void* d_ws, size_t ws_size,
                              hipStream_t stream) {
  (void)in_sizes; (void)n_in; (void)out_size; (void)ws_size;
  const float* x    = (const float*)d_in[0];
  const float* cg   = (const float*)d_in[1];
  const float* Wqkv = (const float*)d_in[2];
  const float* bqkv = (const float*)d_in[3];
  const float* Wout = (const float*)d_in[4];
  const float* bout = (const float*)d_in[5];
  const float* s1   = (const float*)d_in[6];
  const float* b1   = (const float*)d_in[7];
  const float* s2   = (const float*)d_in[8];
  const float* b2   = (const float*)d_in[9];
  const float* Wff1 = (const float*)d_in[10];
  const float* bff1 = (const float*)d_in[11];
  const float* Wff2 = (const float*)d_in[12];
  const float* bff2 = (const float*)d_in[13];
  const float* chl  = (const float*)d_in[14];
  const float* geo  = (const float*)d_in[15];
  float* out = (float*)d_out;

  float* W = (float*)d_ws;
  const size_t U = (size_t)NTOK * D;     // 524288 floats = 2 MB
  // slot plan (8 units = 16 MB total), with lifetime-based reuse:
  float* xt   = W + 0 * U;               // phase1 out, phase2 in
  float* qh   = W + 0 * U;               // overlays xt (dead after QKV gemm)
  float* kh   = W + 1 * U;
  float* qkv  = W + 2 * U;               // 3 units (q,k,v interleaved per token)
  float* ao   = W + 5 * U;
  float* proj = W + 6 * U;
  float* xa   = W + 7 * U;
  float* t2   = W + 5 * U;               // overlays ao (dead after proj gemm)
  float* h1   = W + 0 * U;               // 4 units, overlays qh/kh/qkv[0..1]
  float* f2   = W + 4 * U;               // overlays qkv[2]

  k_pre  <<<NTOK, 256, 0, stream>>>(x, cg, s1, b1, xt);
  k_gemm<0><<<dim3(1536 / 64, NTOK / 64), 256, 0, stream>>>(xt, Wqkv, bqkv, qkv, NTOK, 1536, 512);
  k_rope <<<(NTOK * H) / 4, 256, 0, stream>>>(qkv, chl, qh, kh);
  k_attn <<<NB * H, 256, 0, stream>>>(qh, kh, qkv, chl, geo, ao);
  k_gemm<0><<<dim3(512 / 64, NTOK / 64), 256, 0, stream>>>(ao, Wout, bout, proj, NTOK, 512, 512);
  k_resid<<<NTOK, 256, 0, stream>>>(x, proj, cg, s2, b2, xa, t2);
  k_gemm<1><<<dim3(2048 / 64, NTOK / 64), 256, 0, stream>>>(t2, Wff1, bff1, h1, NTOK, 2048, 512);
  k_gemm<0><<<dim3(512 / 64, NTOK / 64), 256, 0, stream>>>(h1, Wff2, bff2, f2, NTOK, 512, 2048);
  k_final<<<NTOK, 256, 0, stream>>>(xa, f2, cg, out);
}

// Round 2
// 137.018 us; speedup vs baseline: 2.0803x; 2.0803x over previous
//
#include <hip/hip_runtime.h>
#include <math.h>

#define DEV __device__ __forceinline__
typedef unsigned short ush;
typedef __attribute__((ext_vector_type(8))) short s8v;   // 8 bf16 = 4 VGPR
typedef __attribute__((ext_vector_type(4))) float f4v;
typedef __attribute__((ext_vector_type(4))) int i4v;

constexpr int NTOK = 1024;
constexpr int D    = 512;
constexpr int H    = 8;
constexpr int NB   = 16;
constexpr double EPSd = 1e-7;

DEV ush f2b(float v) {                      // fp32 -> bf16 RNE
  unsigned u = __float_as_uint(v);
  return (ush)((u + 0x7fffu + ((u >> 16) & 1u)) >> 16);
}
DEV float b2f(ush u) { return __uint_as_float(((unsigned)u) << 16); }

// ---------------- reductions ----------------
DEV double wave_sum(double v) {
#pragma unroll
  for (int m = 32; m; m >>= 1) v += __shfl_xor(v, m, 64);
  return v;
}
DEV double block_sum(double v, double* scratch) {
  v = wave_sum(v);
  __syncthreads();
  if ((threadIdx.x & 63) == 0) scratch[threadIdx.x >> 6] = v;
  __syncthreads();
  return scratch[0] + scratch[1] + scratch[2] + scratch[3];
}

// ---------------- weight transpose-cast: W[K][N] f32 -> WT[N][K] bf16 (hi[/lo]) ----------------
template <int SPLIT>
__global__ void k_tcast(const float* __restrict__ src, ush* __restrict__ dh,
                        ush* __restrict__ dl, int K, int N) {
  __shared__ float t[32][33];
  const int n0 = blockIdx.x * 32, k0 = blockIdx.y * 32;
  const int tx = threadIdx.x & 31, ty = threadIdx.x >> 5;
  for (int i = ty; i < 32; i += 8) t[i][tx] = src[(size_t)(k0 + i) * N + n0 + tx];
  __syncthreads();
  for (int i = ty; i < 32; i += 8) {
    float v = t[tx][i];
    ush h = f2b(v);
    dh[(size_t)(n0 + i) * K + k0 + tx] = h;
    if (SPLIT) dl[(size_t)(n0 + i) * K + k0 + tx] = f2b(v - b2f(h));
  }
}

// ---------------- phase 1: logmap0 -> LN -> expmap0 -> logmap0 (fused), bf16 hi/lo out ----------
__global__ void k_pre(const float* __restrict__ x, const float* __restrict__ cg,
                      const float* __restrict__ s1, const float* __restrict__ b1,
                      ush* __restrict__ xth, ush* __restrict__ xtl) {
  __shared__ double scratch[4];
  const int tok = blockIdx.x, t = threadIdx.x;
  const float* row = x + (size_t)tok * D;
  float v0 = row[t], v1 = row[t + 256];
  double c = (double)cg[0];
  double sc = sqrt(c); if (sc < EPSd) sc = EPSd;
  double yn = sqrt(block_sum((double)v0 * v0 + (double)v1 * v1, scratch));
  double arg0 = yn; if (arg0 > 1.0 - EPSd) arg0 = 1.0 - EPSd;
  double f = (yn < EPSd) ? 0.0 : atanh(arg0) / sc / fmax(yn, EPSd);
  double u0 = f * v0, u1 = f * v1;
  double mu  = block_sum(u0 + u1, scratch) / D;
  double su2 = block_sum(u0 * u0 + u1 * u1, scratch);
  double rs = 1.0 / sqrt(su2 / D - mu * mu + 1e-6);
  double w0 = (u0 - mu) * rs * (double)s1[t]       + (double)b1[t];
  double w1 = (u1 - mu) * rs * (double)s1[t + 256] + (double)b1[t + 256];
  double vn = sqrt(block_sum(w0 * w0 + w1 * w1, scratch));
  double F = 0.0;
  if (vn >= EPSd) {
    double mag_e = tanh(sc * fmax(vn, EPSd)) / sc;
    double a2 = fmin(mag_e, 1.0 - EPSd);
    F = atanh(a2) / (sc * vn);
  }
  float o0 = (float)(F * w0), o1 = (float)(F * w1);
  ush h0 = f2b(o0), h1 = f2b(o1);
  size_t base = (size_t)tok * D + t;
  xth[base] = h0;       xth[base + 256] = h1;
  xtl[base] = f2b(o0 - b2f(h0));
  xtl[base + 256] = f2b(o1 - b2f(h1));
}

// ---------------- bf16 MFMA GEMM: C[M,N] = A[M,K] @ BT[N,K]^T + bias ----------------
// SPLIT: hi/lo 3-pass (fp32-class accuracy). OBF16: bf16 out (with optional GELU).
template <int SPLIT, int GELU, int OBF16>
__global__ __launch_bounds__(256) void k_mm(
    const ush* __restrict__ Ah, const ush* __restrict__ Al,
    const ush* __restrict__ Bh, const ush* __restrict__ Bl,
    const float* __restrict__ bias, float* __restrict__ Cf,
    ush* __restrict__ Cb, int M, int N, int K) {
  __shared__ __align__(16) ush As[SPLIT + 1][64][40];   // pad 32->40: 2-way banks (free)
  __shared__ __align__(16) ush Bs[SPLIT + 1][64][40];
  const int tid = threadIdx.x;
  const int lane = tid & 63, wid = tid >> 6;
  const int wr = (wid >> 1) * 32, wc = (wid & 1) * 32;
  const int lr = lane & 15, lg = lane >> 4;
  const size_t r0 = blockIdx.y * 64, c0 = blockIdx.x * 64;
  const int srow = tid >> 2, skoff = (tid & 3) * 8;
  const size_t aoff = (r0 + srow) * (size_t)K + skoff;
  const size_t boff = (c0 + srow) * (size_t)K + skoff;
  const f4v z = {0.f, 0.f, 0.f, 0.f};
  f4v acc[2][2]; acc[0][0] = z; acc[0][1] = z; acc[1][0] = z; acc[1][1] = z;
  for (int k0 = 0; k0 < K; k0 += 32) {
    *(i4v*)&As[0][srow][skoff] = *(const i4v*)(Ah + aoff + k0);
    *(i4v*)&Bs[0][srow][skoff] = *(const i4v*)(Bh + boff + k0);
    if (SPLIT) {
      *(i4v*)&As[SPLIT][srow][skoff] = *(const i4v*)(Al + aoff + k0);
      *(i4v*)&Bs[SPLIT][srow][skoff] = *(const i4v*)(Bl + boff + k0);
    }
    __syncthreads();
    s8v ah0 = *(const s8v*)&As[0][wr + lr][lg * 8];
    s8v ah1 = *(const s8v*)&As[0][wr + 16 + lr][lg * 8];
    s8v bh0 = *(const s8v*)&Bs[0][wc + lr][lg * 8];
    s8v bh1 = *(const s8v*)&Bs[0][wc + 16 + lr][lg * 8];
    acc[0][0] = __builtin_amdgcn_mfma_f32_16x16x32_bf16(ah0, bh0, acc[0][0], 0, 0, 0);
    acc[0][1] = __builtin_amdgcn_mfma_f32_16x16x32_bf16(ah0, bh1, acc[0][1], 0, 0, 0);
    acc[1][0] = __builtin_amdgcn_mfma_f32_16x16x32_bf16(ah1, bh0, acc[1][0], 0, 0, 0);
    acc[1][1] = __builtin_amdgcn_mfma_f32_16x16x32_bf16(ah1, bh1, acc[1][1], 0, 0, 0);
    if (SPLIT) {
      s8v al0 = *(const s8v*)&As[SPLIT][wr + lr][lg * 8];
      s8v al1 = *(const s8v*)&As[SPLIT][wr + 16 + lr][lg * 8];
      s8v bl0 = *(const s8v*)&Bs[SPLIT][wc + lr][lg * 8];
      s8v bl1 = *(const s8v*)&Bs[SPLIT][wc + 16 + lr][lg * 8];
      acc[0][0] = __builtin_amdgcn_mfma_f32_16x16x32_bf16(ah0, bl0, acc[0][0], 0, 0, 0);
      acc[0][1] = __builtin_amdgcn_mfma_f32_16x16x32_bf16(ah0, bl1, acc[0][1], 0, 0, 0);
      acc[1][0] = __builtin_amdgcn_mfma_f32_16x16x32_bf16(ah1, bl0, acc[1][0], 0, 0, 0);
      acc[1][1] = __builtin_amdgcn_mfma_f32_16x16x32_bf16(ah1, bl1, acc[1][1], 0, 0, 0);
      acc[0][0] = __builtin_amdgcn_mfma_f32_16x16x32_bf16(al0, bh0, acc[0][0], 0, 0, 0);
      acc[0][1] = __builtin_amdgcn_mfma_f32_16x16x32_bf16(al0, bh1, acc[0][1], 0, 0, 0);
      acc[1][0] = __builtin_amdgcn_mfma_f32_16x16x32_bf16(al1, bh0, acc[1][0], 0, 0, 0);
      acc[1][1] = __builtin_amdgcn_mfma_f32_16x16x32_bf16(al1, bh1, acc[1][1], 0, 0, 0);
    }
    __syncthreads();
  }
#pragma unroll
  for (int fi = 0; fi < 2; ++fi)
#pragma unroll
    for (int fj = 0; fj < 2; ++fj) {
      const size_t row = r0 + wr + fi * 16 + lg * 4;
      const size_t col = c0 + wc + fj * 16 + lr;
      const float bv = bias[col];
#pragma unroll
      for (int e = 0; e < 4; ++e) {
        float v = acc[fi][fj][e] + bv;
        if (GELU) {
          float x3 = v * v * v;
          v = 0.5f * v * (1.0f + tanhf(0.7978845608028654f * (v + 0.044715f * x3)));
        }
        if (OBF16) Cb[(row + e) * N + col] = f2b(v);
        else       Cf[(row + e) * N + col] = v;
      }
    }
}

// ---------------- attention: fused RoPE + per-head expmap0 + hyperbolic dist + softmax + PV ----
__global__ __launch_bounds__(256) void k_attn(
    const float* __restrict__ qkv, const float* __restrict__ chl,
    const float* __restrict__ geo, ush* __restrict__ ao) {
  __shared__ float Qs[64][65];
  __shared__ float Ks[64][65];
  __shared__ double q2s[64], k2s[64], fqv[64], fkv[64];
  const int be = blockIdx.x >> 3, h = blockIdx.x & 7;
  const int tid = threadIdx.x;
  const double ch = log1p(exp((double)chl[h]));
  double sc = sqrt(ch); if (sc < EPSd) sc = EPSd;
  // stage q,k with RoPE applied (pos within block = row s)
  for (int l = tid; l < 64 * 32; l += 256) {
    int s = l >> 5, j = l & 31;
    const float* base = qkv + (size_t)(be * 64 + s) * 1536 + h * 64;
    double qa = base[j],        qb = base[j + 32];
    double ka = base[512 + j],  kb = base[512 + j + 32];
    double fj = exp(-log(10000.0) * (double)j / 32.0);
    double th = (double)s * fj;
    double ct = cos(th), st = sin(th);
    Qs[s][j]      = (float)(qa * ct - qb * st);
    Qs[s][j + 32] = (float)(qa * st + qb * ct);
    Ks[s][j]      = (float)(ka * ct - kb * st);
    Ks[s][j + 32] = (float)(ka * st + kb * ct);
  }
  __syncthreads();
  // per-row expmap0 factors (rows stay unscaled in LDS; factors folded in later)
  if (tid < 128) {
    int i = tid & 63;
    const float* P = (tid < 64) ? &Qs[i][0] : &Ks[i][0];
    double acc = 0;
    for (int d2 = 0; d2 < 64; ++d2) { double v = P[d2]; acc += v * v; }
    double n = sqrt(acc);
    double m = tanh(sc * fmax(n, EPSd)) / sc;
    double f = (n < EPSd) ? 0.0 : m / fmax(n, EPSd);
    if (m >= 1.0) f *= (1.0 - EPSd) / m;
    if (tid < 64) { fqv[i] = f; q2s[i] = f * f * acc; }
    else          { fkv[i] = f; k2s[i] = f * f * acc; }
  }
  __syncthreads();
  const int i = tid >> 2, g = tid & 3;
  float gacc[16];
#pragma unroll
  for (int jj = 0; jj < 16; ++jj) gacc[jj] = 0.f;
  for (int d2 = 0; d2 < 64; ++d2) {
    float qv = Qs[i][d2];
#pragma unroll
    for (int jj = 0; jj < 16; ++jj) gacc[jj] += qv * Ks[g * 16 + jj][d2];
  }
  const double gs = (double)geo[h];
  const double q2 = q2s[i], fqi = fqv[i];
  float lg[16];
  float mx = -1e30f;
#pragma unroll
  for (int jj = 0; jj < 16; ++jj) {
    double gq = fqi * fkv[g * 16 + jj] * (double)gacc[jj];
    double k2 = k2s[g * 16 + jj];
    double A  = 1.0 - 2.0 * ch * gq + ch * k2;
    double Bv = 1.0 - ch * q2;
    double n2 = A * A * q2 - 2.0 * A * Bv * gq + Bv * Bv * k2;
    if (n2 < 0.0) n2 = 0.0;
    double den = 1.0 - 2.0 * ch * gq + ch * ch * q2 * k2;
    if (den < EPSd) den = EPSd;
    double r = sqrt(n2) / den;
    if (r >= 1.0) r = 1.0 - EPSd;
    double arg = sc * r; if (arg > 1.0 - EPSd) arg = 1.0 - EPSd;
    float l = (float)(-gs * (2.0 * atanh(arg) / sc));
    lg[jj] = l; mx = fmaxf(mx, l);
  }
  mx = fmaxf(mx, __shfl_xor(mx, 1, 64));
  mx = fmaxf(mx, __shfl_xor(mx, 2, 64));
  float pv[16]; float sum = 0.f;
#pragma unroll
  for (int jj = 0; jj < 16; ++jj) { pv[jj] = expf(lg[jj] - mx); sum += pv[jj]; }
  sum += __shfl_xor(sum, 1, 64);
  sum += __shfl_xor(sum, 2, 64);
  float inv = 1.0f / sum;
  __syncthreads();
#pragma unroll
  for (int jj = 0; jj < 16; ++jj) Qs[i][g * 16 + jj] = pv[jj] * inv;
  for (int l = tid; l < 64 * 64; l += 256) {
    int s = l >> 6, d2 = l & 63;
    Ks[s][d2] = qkv[(size_t)(be * 64 + s) * 1536 + 1024 + h * 64 + d2];
  }
  __syncthreads();
  float oacc[16];
#pragma unroll
  for (int dd = 0; dd < 16; ++dd) oacc[dd] = 0.f;
  for (int jv = 0; jv < 64; ++jv) {
    float p = Qs[i][jv];
#pragma unroll
    for (int dd = 0; dd < 16; ++dd) oacc[dd] += p * Ks[jv][g * 16 + dd];
  }
#pragma unroll
  for (int dd = 0; dd < 16; ++dd)
    ao[(size_t)(be * 64 + i) * D + h * 64 + g * 16 + dd] = f2b(oacc[dd]);
}

// ---------------- residual: expmap0(proj) -> mobius add -> LN2 chain ----------------
__global__ void k_resid(const float* __restrict__ x, const float* __restrict__ proj,
                        const float* __restrict__ cg, const float* __restrict__ s2,
                        const float* __restrict__ b2, float* __restrict__ xa,
                        ush* __restrict__ t2) {
  __shared__ double scratch[4];
  const int tok = blockIdx.x, t = threadIdx.x;
  const float* xr = x    + (size_t)tok * D;
  const float* pr = proj + (size_t)tok * D;
  float x0 = xr[t], x1 = xr[t + 256];
  float p0 = pr[t], p1 = pr[t + 256];
  double c = (double)cg[0];
  double sc = sqrt(c); if (sc < EPSd) sc = EPSd;
  double xx = block_sum((double)x0 * x0 + (double)x1 * x1, scratch);
  double pp = block_sum((double)p0 * p0 + (double)p1 * p1, scratch);
  double xp = block_sum((double)x0 * p0 + (double)x1 * p1, scratch);
  double pn = sqrt(pp);
  double me = tanh(sc * fmax(pn, EPSd)) / sc;
  double fs = (pn < EPSd) ? 0.0 : me / fmax(pn, EPSd);
  if (me >= 1.0) fs *= (1.0 - EPSd) / me;
  double y2 = fs * fs * pp, xy = fs * xp;
  double a = 1.0 + 2.0 * c * xy + c * y2;
  double b = 1.0 - c * xx;
  double den = 1.0 + 2.0 * c * xy + c * c * xx * y2;
  if (den < EPSd) den = EPSd;
  double zn = sqrt(fmax(a * a * xx + 2.0 * a * b * xy + b * b * y2, 0.0)) / den;
  double zs = 1.0 / den;
  if (zn >= 1.0) zs *= (1.0 - EPSd) / zn;
  double xan = (zn >= 1.0) ? (1.0 - EPSd) : zn;
  double A0 = zs * a, B0 = zs * b * fs;
  double xa0 = A0 * x0 + B0 * p0, xa1 = A0 * x1 + B0 * p1;
  xa[(size_t)tok * D + t]       = (float)xa0;
  xa[(size_t)tok * D + t + 256] = (float)xa1;
  double fl = 0.0;
  if (xan >= EPSd) fl = atanh(fmin(xan, 1.0 - EPSd)) / (sc * fmax(xan, EPSd));
  double u0 = fl * xa0, u1 = fl * xa1;
  double mu  = block_sum(u0 + u1, scratch) / D;
  double su2 = block_sum(u0 * u0 + u1 * u1, scratch);
  double rs = 1.0 / sqrt(su2 / D - mu * mu + 1e-6);
  double w0 = (u0 - mu) * rs * (double)s2[t]       + (double)b2[t];
  double w1 = (u1 - mu) * rs * (double)s2[t + 256] + (double)b2[t + 256];
  double vn = sqrt(block_sum(w0 * w0 + w1 * w1, scratch));
  double F = 0.0;
  if (vn >= EPSd) {
    double mag_e = tanh(sc * fmax(vn, EPSd)) / sc;
    F = atanh(fmin(mag_e, 1.0 - EPSd)) / (sc * vn);
  }
  t2[(size_t)tok * D + t]       = f2b((float)(F * w0));
  t2[(size_t)tok * D + t + 256] = f2b((float)(F * w1));
}

// ---------------- final: expmap0(ffn) -> mobius add -> out ----------------
__global__ void k_final(const float* __restrict__ xa, const float* __restrict__ f2,
                        const float* __restrict__ cg, float* __restrict__ out) {
  __shared__ double scratch[4];
  const int tok = blockIdx.x, t = threadIdx.x;
  const float* ar = xa + (size_t)tok * D;
  const float* fr = f2 + (size_t)tok * D;
  float x0 = ar[t], x1 = ar[t + 256];
  float p0 = fr[t], p1 = fr[t + 256];
  double c = (double)cg[0];
  double sc = sqrt(c); if (sc < EPSd) sc = EPSd;
  double xx = block_sum((double)x0 * x0 + (double)x1 * x1, scratch);
  double pp = block_sum((double)p0 * p0 + (double)p1 * p1, scratch);
  double xp = block_sum((double)x0 * p0 + (double)x1 * p1, scratch);
  double pn = sqrt(pp);
  double me = tanh(sc * fmax(pn, EPSd)) / sc;
  double fs = (pn < EPSd) ? 0.0 : me / fmax(pn, EPSd);
  if (me >= 1.0) fs *= (1.0 - EPSd) / me;
  double y2 = fs * fs * pp, xy = fs * xp;
  double a = 1.0 + 2.0 * c * xy + c * y2;
  double b = 1.0 - c * xx;
  double den = 1.0 + 2.0 * c * xy + c * c * xx * y2;
  if (den < EPSd) den = EPSd;
  double zn = sqrt(fmax(a * a * xx + 2.0 * a * b * xy + b * b * y2, 0.0)) / den;
  double zs = 1.0 / den;
  if (zn >= 1.0) zs *= (1.0 - EPSd) / zn;
  double A0 = zs * a, B0 = zs * b * fs;
  out[(size_t)tok * D + t]       = (float)(A0 * x0 + B0 * p0);
  out[(size_t)tok * D + t + 256] = (float)(A0 * x1 + B0 * p1);
}

// ---------------- launch ----------------
extern "C" void kernel_launch(void* const* d_in, const int* in_sizes, int n_in,
                              void* d_out, int out_size, void* d_ws, size_t ws_size,
                              hipStream_t stream) {
  (void)in_sizes; (void)n_in; (void)out_size; (void)ws_size;
  const float* x    = (const float*)d_in[0];
  const float* cg   = (const float*)d_in[1];
  const float* Wqkv = (const float*)d_in[2];
  const float* bqkv = (const float*)d_in[3];
  const float* Wout = (const float*)d_in[4];
  const float* bout = (const float*)d_in[5];
  const float* s1   = (const float*)d_in[6];
  const float* b1   = (const float*)d_in[7];
  const float* s2   = (const float*)d_in[8];
  const float* b2   = (const float*)d_in[9];
  const float* Wff1 = (const float*)d_in[10];
  const float* bff1 = (const float*)d_in[11];
  const float* Wff2 = (const float*)d_in[12];
  const float* bff2 = (const float*)d_in[13];
  const float* chl  = (const float*)d_in[14];
  const float* geo  = (const float*)d_in[15];
  float* out = (float*)d_out;

  // ---- workspace layout (bytes), lifetime-overlaid; peak 15.5 MB of the 16 MB pool ----
  char* base = (char*)d_ws;
  ush* WqkvT_h = (ush*)(base + 0);          // 1.5 MB  [dead after QKV gemm]
  ush* WqkvT_l = (ush*)(base + 1572864);    // 1.5 MB  [dead after QKV gemm]
  ush* WoutT   = (ush*)(base + 3145728);    // 0.5 MB  [dead after out-proj]
  ush* Wff1T   = (ush*)(base + 3670016);    // 2 MB
  ush* Wff2T   = (ush*)(base + 5767168);    // 2 MB
  const size_t R = 7864320;
  float* qkv  = (float*)(base + R);             // 6 MB [qkv gemm .. attn]
  ush*   xt_h = (ush*)(base + R + 6291456);     // 1 MB [pre .. qkv gemm]
  ush*   xt_l = (ush*)(base + R + 7340032);     // 1 MB
  ush*   ao   = xt_h;                           // 1 MB [attn .. out-proj]
  float* proj = (float*)(base + R);             // 2 MB [out-proj .. resid] (qkv slot)
  float* xa   = (float*)(base + 0);             // 2 MB [resid .. final]   (WqkvT slot)
  ush*   t2   = (ush*)(base + 2097152);         // 1 MB [resid .. ff1]     (WqkvT_l tail)
  ush*   h1   = (ush*)(base + R);               // 4 MB [ff1 .. ff2]       (qkv/proj slot)
  float* f2   = (float*)(base + R + 4194304);   // 2 MB [ff2 .. final]

  k_tcast<1><<<dim3(1536 / 32, 512 / 32),  256, 0, stream>>>(Wqkv, WqkvT_h, WqkvT_l, 512, 1536);
  k_tcast<0><<<dim3(512 / 32, 512 / 32),   256, 0, stream>>>(Wout, WoutT, nullptr, 512, 512);
  k_tcast<0><<<dim3(2048 / 32, 512 / 32),  256, 0, stream>>>(Wff1, Wff1T, nullptr, 512, 2048);
  k_tcast<0><<<dim3(512 / 32, 2048 / 32),  256, 0, stream>>>(Wff2, Wff2T, nullptr, 2048, 512);

  k_pre<<<NTOK, 256, 0, stream>>>(x, cg, s1, b1, xt_h, xt_l);
  k_mm<1, 0, 0><<<dim3(1536 / 64, NTOK / 64), 256, 0, stream>>>(
      xt_h, xt_l, WqkvT_h, WqkvT_l, bqkv, qkv, nullptr, NTOK, 1536, 512);
  k_attn<<<NB * H, 256, 0, stream>>>(qkv, chl, geo, ao);
  k_mm<0, 0, 0><<<dim3(512 / 64, NTOK / 64), 256, 0, stream>>>(
      ao, nullptr, WoutT, nullptr, bout, proj, nullptr, NTOK, 512, 512);
  k_resid<<<NTOK, 256, 0, stream>>>(x, proj, cg, s2, b2, xa, t2);
  k_mm<0, 1, 1><<<dim3(2048 / 64, NTOK / 64), 256, 0, stream>>>(
      t2, nullptr, Wff1T, nullptr, bff1, nullptr, h1, NTOK, 2048, 512);
  k_mm<0, 0, 0><<<dim3(512 / 64, NTOK / 64), 256, 0, stream>>>(
      h1, nullptr, Wff2T, nullptr, bff2, f2, nullptr, NTOK, 512, 2048);
  k_final<<<NTOK, 256, 0, stream>>>(xa, f2, cg, out);
}